// Round 4
// baseline (213.990 us; speedup 1.0000x reference)
//
#include <hip/hip_runtime.h>

// Problem constants (fixed by reference setup_inputs): B=32, C=3, H=W=512.
#define HW_PLANE (512 * 512)      // 2^18 pixels per (b,c) plane
#define N_ELEMS (32 * 3 * HW_PLANE)
#define NBLOCKS (96 * 32)         // 3072 partials

// Grid: (32 chunks, 3 channels, 32 batches). Each block streams a contiguous
// 32 KB slice of ONE (b,c) plane from x and y (copy-like access; bbox, b, c
// all block-uniform -> SALU). Each thread issues ALL 16 float4 loads (8 x +
// 8 y) before any use: R2/R3 showed runtime invariant at waves*inflight ~= 40
// -> outstanding-request-limited; this quadruples per-wave MLP.
__global__ __launch_bounds__(256) void mae_bbox_kernel(
    const float* __restrict__ x, const float* __restrict__ y,
    const int* __restrict__ bbox, float* __restrict__ ws) {

    const int chunk = blockIdx.x;        // 0..31: which 1/32 of the plane
    const int c     = blockIdx.y;        // 0..2
    const int b     = blockIdx.z;        // 0..31
    const int tid   = threadIdx.x;

    const int* bb = bbox + (b << 3);     // block-uniform -> s_load
    const int xmin = min(min(bb[0], bb[2]), min(bb[4], bb[6]));
    const int xmax = max(max(bb[0], bb[2]), max(bb[4], bb[6]));
    const int ymin = min(min(bb[1], bb[3]), min(bb[5], bb[7]));
    const int ymax = max(max(bb[1], bb[3]), max(bb[5], bb[7]));
    const bool cond = (xmin > 5) && (xmax < 507) && (ymin > 5) && (ymax < 507);

    // flat element offset of this thread's first quad
    const size_t base = ((size_t)(b * 3 + c) << 18) + ((size_t)chunk << 13) + (size_t)(tid << 2);

    // ---- batched loads: 16 independent float4 loads in flight ----
    float4 xv[8], yv[8];
#pragma unroll
    for (int k = 0; k < 8; ++k)
        xv[k] = *reinterpret_cast<const float4*>(x + base + (size_t)(k << 10));
#pragma unroll
    for (int k = 0; k < 8; ++k)
        yv[k] = *reinterpret_cast<const float4*>(y + base + (size_t)(k << 10));

    // ---- weights ----
    // thread's pixel geometry: successive k are exactly 2 rows apart, same cols
    const int w0     = (tid << 2) & 511;          // col of quad's first pixel
    const int h_base = (chunk << 4) + (tid >> 7); // row for k=0

    int   fx[4];
    bool  incol[4];
#pragma unroll
    for (int j = 0; j < 4; ++j) {
        const int wx = w0 + j;
        incol[j] = (wx >= xmin) && (wx < xmax);
        fx[j] = incol[j] ? 5
              : ((wx >= xmin - 5 && wx < xmin) ? (wx - xmin + 6)
              : ((wx >= xmax && wx < xmax + 5) ? (5 - (wx - xmax)) : 0));
    }

    float acc = 0.0f;
#pragma unroll
    for (int k = 0; k < 8; ++k) {
        const int h = h_base + (k << 1);
        const bool inrow = (h >= ymin) && (h < ymax);
        const int fy = inrow ? 5
                     : ((h >= ymin - 5 && h < ymin) ? (h - ymin + 6)
                     : ((h >= ymax && h < ymax + 5) ? (5 - (h - ymax)) : 0));

        float wq[4];
#pragma unroll
        for (int j = 0; j < 4; ++j) {
            const bool inside = inrow && incol[j];
            float wv = inside ? 100.0f : 1.0f;
            if (cond && (fy > 0) && (fx[j] > 0) && !inside)
                wv = (float)min(fy, fx[j]) * 20.0f;  // min(fy,fx)/m*ALPHA, m=5, ALPHA=100
            wq[j] = wv;
        }

        acc = fmaf(fabsf(xv[k].x - yv[k].x), wq[0], acc);
        acc = fmaf(fabsf(xv[k].y - yv[k].y), wq[1], acc);
        acc = fmaf(fabsf(xv[k].z - yv[k].z), wq[2], acc);
        acc = fmaf(fabsf(xv[k].w - yv[k].w), wq[3], acc);
    }

    // wave-64 shuffle reduce
#pragma unroll
    for (int off = 32; off > 0; off >>= 1) acc += __shfl_down(acc, off, 64);

    __shared__ float sred[4];
    const int lane = tid & 63;
    const int wid  = tid >> 6;
    if (lane == 0) sred[wid] = acc;
    __syncthreads();
    if (tid == 0) {
        const int bid = ((b * 3 + c) << 5) + chunk;   // 0..3071
        ws[bid] = sred[0] + sred[1] + sred[2] + sred[3];
    }
}

// Stage 2: one block sums the 3072 partials and writes the mean.
__global__ __launch_bounds__(256) void finalize_kernel(
    const float* __restrict__ ws, float* __restrict__ out) {
    float acc = 0.0f;
#pragma unroll
    for (int i = 0; i < NBLOCKS / 256; ++i)
        acc += ws[i * 256 + threadIdx.x];

#pragma unroll
    for (int off = 32; off > 0; off >>= 1) acc += __shfl_down(acc, off, 64);

    __shared__ float sred[4];
    const int lane = threadIdx.x & 63;
    const int wid  = threadIdx.x >> 6;
    if (lane == 0) sred[wid] = acc;
    __syncthreads();
    if (threadIdx.x == 0)
        out[0] = (sred[0] + sred[1] + sred[2] + sred[3]) * (1.0f / (float)N_ELEMS);
}

extern "C" void kernel_launch(void* const* d_in, const int* in_sizes, int n_in,
                              void* d_out, int out_size, void* d_ws, size_t ws_size,
                              hipStream_t stream) {
    const float* x    = (const float*)d_in[0];
    const float* y    = (const float*)d_in[1];
    const int*   bbox = (const int*)d_in[2];
    float* out = (float*)d_out;
    float* ws  = (float*)d_ws;   // needs NBLOCKS*4 = 12 KB scratch

    dim3 grid(32, 3, 32);        // chunk, channel, batch
    mae_bbox_kernel<<<grid, 256, 0, stream>>>(x, y, bbox, ws);
    finalize_kernel<<<1, 256, 0, stream>>>(ws, out);
}